// Round 23
// baseline (63.437 us; speedup 1.0000x reference)
//
#include <hip/hip_runtime.h>
#include <math.h>

#define B_ 2
#define T_ 1024
#define C_ 1024
#define NH 16
#define DH 64
#define M_ 128
#define LCH 64
#define NC (T_/LCH)          // 16 chunks
#define DEXT 80              // 64 d + den-row(64) + pad to 5 tiles

constexpr float SCALE = 0.125f;              // 1/sqrt(64)
constexpr float EPSV = 1e-6f;
constexpr float INV_SQRT_M = 0.088388347648318447f;  // 1/sqrt(128)

typedef _Float16 f16;
typedef f16 f16x4 __attribute__((ext_vector_type(4)));
typedef f16 f16x8 __attribute__((ext_vector_type(8)));
typedef float f32x4 __attribute__((ext_vector_type(4)));

typedef const __attribute__((address_space(1))) void* as1_cvoid_p;
typedef __attribute__((address_space(3))) void* as3_void_p;

#define MFMA16 __builtin_amdgcn_mfma_f32_16x16x32_f16

__device__ __forceinline__ void gload16(const void* g, void* l) {
  __builtin_amdgcn_global_load_lds((as1_cvoid_p)g, (as3_void_p)l, 16, 0, 0);
}

// swizzled element index: row of (slots*8) f16, 16B-slot XOR'd by low row bits
__device__ __forceinline__ int sw8(int row, int slot)  { return row * 64  + ((slot ^ (row & 7))  << 3); }
__device__ __forceinline__ int sw16(int row, int slot) { return row * 128 + ((slot ^ (row & 15)) << 3); }

// ---------- prep: x->fp16, omega transpose, vT den-rows init, both weight transposes ----------
__global__ __launch_bounds__(256) void prep_kernel(const float* __restrict__ x,
                                                   const float* __restrict__ omega,
                                                   const float* __restrict__ Wa,
                                                   const float* __restrict__ Wp,
                                                   f16* __restrict__ x16,
                                                   f16* __restrict__ omT,
                                                   f16* __restrict__ vT,
                                                   f16* __restrict__ B16,
                                                   f16* __restrict__ B16p) {
  __shared__ float tile[32][33];
  int bid = blockIdx.x, tid = threadIdx.x;
  if (bid < 2048) {
    int i = (bid * 256 + tid) * 4;
    float4 v = *(const float4*)&x[i];
    f16x4 o = {(f16)v.x, (f16)v.y, (f16)v.z, (f16)v.w};
    *(f16x4*)&x16[i] = o;
  } else if (bid < 2080) {
    int e = (bid - 2048) * 256 + tid;
    int d = e >> 7, m = e & 127;
    omT[m * 64 + d] = (f16)omega[e];
  } else if (bid < 2592) {
    int idx = bid - 2080;             // 0..511
    int bh = idx >> 4, dr = idx & 15;
    f16 val = (dr == 0) ? (f16)1.0f : (f16)0.0f;
    f16x4 o = {val, val, val, val};
    *(f16x4*)&vT[((size_t)bh * DEXT + 64 + dr) * 1024 + tid * 4] = o;
  } else {
    int tb = bid - 2592;
    const float* in; f16* out; int N, n0, k0;
    if (tb < 3072) { in = Wa; out = B16;  N = 3072; n0 = (tb % 96) * 32; k0 = (tb / 96) * 32; }
    else { tb -= 3072; in = Wp; out = B16p; N = 1024; n0 = (tb & 31) * 32; k0 = (tb >> 5) * 32; }
    // vectorized transpose: 1 float4 load + 1 f16x4 store per thread (G13)
    {
      int row = tid >> 3, col4 = (tid & 7) * 4;       // tile row = k-rel, col = n-rel
      float4 v = *(const float4*)&in[(size_t)(k0 + row) * N + n0 + col4];
      tile[row][col4 + 0] = v.x; tile[row][col4 + 1] = v.y;
      tile[row][col4 + 2] = v.z; tile[row][col4 + 3] = v.w;
    }
    __syncthreads();
    {
      int n = tid >> 3, k4 = (tid & 7) * 4;
      f16x4 o = {(f16)tile[k4 + 0][n], (f16)tile[k4 + 1][n],
                 (f16)tile[k4 + 2][n], (f16)tile[k4 + 3][n]};
      *(f16x4*)&out[(size_t)(n0 + n) * 1024 + k0 + k4] = o;
    }
  }
}

// ---------- qkv GEMM (fp16 MFMA, 128x64 tile, BK=64, dbuf prefetch, XCD swizzle) --------------
// qk blocks use LDS-transpose epilogue: 32 scalar stores -> 4 coalesced f16x8 stores per thread
__global__ __launch_bounds__(256) void gemm_qkv_kernel(
    const f16* __restrict__ A, const f16* __restrict__ B,
    const float* __restrict__ bias, f16* __restrict__ qk16, f16* __restrict__ vT16) {
  __shared__ f16 As[2][128 * 64];
  __shared__ f16 Bs[2][64 * 64];
  const int tid = threadIdx.x;
  const int wid = tid >> 6, lane = tid & 63;
  // XCD-aware swizzle: 768 blocks, chunk 96 per XCD => 2 A row-panels resident per XCD L2
  const int bid = blockIdx.x;
  const int sbid = (bid & 7) * 96 + (bid >> 3);
  const int bm = (sbid / 48) * 128, bn = (sbid % 48) * 64;
  const int wr = (wid >> 1) * 64, wc = (wid & 1) * 32;
  const int srow = lane >> 3, slot = lane & 7;
  const int frow = lane & 15, fkc = lane >> 4;
  f32x4 acc[4][2];
#pragma unroll
  for (int mi = 0; mi < 4; ++mi)
#pragma unroll
    for (int ni = 0; ni < 2; ++ni) acc[mi][ni] = f32x4{0.f, 0.f, 0.f, 0.f};

  auto STAGE = [&](int buf, int kt) {
#pragma unroll
    for (int i = 0; i < 4; ++i) {
      int row = i * 32 + wid * 8 + srow;
      gload16(&A[(size_t)(bm + row) * 1024 + kt + ((slot ^ (row & 7)) << 3)],
              (char*)As[buf] + i * 4096 + wid * 1024);
    }
#pragma unroll
    for (int i = 0; i < 2; ++i) {
      int row = i * 32 + wid * 8 + srow;
      gload16(&B[(size_t)(bn + row) * 1024 + kt + ((slot ^ (row & 7)) << 3)],
              (char*)Bs[buf] + i * 4096 + wid * 1024);
    }
  };
  STAGE(0, 0);
  for (int kt = 0; kt < 1024; kt += 64) {
    const int cur = (kt >> 6) & 1;
    if (kt + 64 < 1024) {
      STAGE(cur ^ 1, kt + 64);
      asm volatile("s_waitcnt vmcnt(6)" ::: "memory");
    } else {
      asm volatile("s_waitcnt vmcnt(0)" ::: "memory");
    }
    __builtin_amdgcn_s_barrier();
    asm volatile("" ::: "memory");
    f16x8 af[4][2], bf[2][2];
#pragma unroll
    for (int mi = 0; mi < 4; ++mi)
#pragma unroll
      for (int kk = 0; kk < 2; ++kk)
        af[mi][kk] = *(const f16x8*)&As[cur][sw8(wr + mi * 16 + frow, kk * 4 + fkc)];
#pragma unroll
    for (int ni = 0; ni < 2; ++ni)
#pragma unroll
      for (int kk = 0; kk < 2; ++kk)
        bf[ni][kk] = *(const f16x8*)&Bs[cur][sw8(wc + ni * 16 + frow, kk * 4 + fkc)];
#pragma unroll
    for (int kk = 0; kk < 2; ++kk)
#pragma unroll
      for (int mi = 0; mi < 4; ++mi)
#pragma unroll
        for (int ni = 0; ni < 2; ++ni)
          acc[mi][ni] = MFMA16(af[mi][kk], bf[ni][kk], acc[mi][ni], 0, 0, 0);
    asm volatile("" ::: "memory");
    __builtin_amdgcn_s_barrier();
  }
  if (bn < 2048) {
    // qk half: LDS-transpose epilogue (staging LDS dead after main loop)
    f16* ytile = As[0];               // 128*64 f16 = exactly the tile
#pragma unroll
    for (int ni = 0; ni < 2; ++ni) {
      int col = wc + ni * 16 + frow;
      float bv = bias[bn + col];
#pragma unroll
      for (int mi = 0; mi < 4; ++mi) {
        int row0 = wr + mi * 16 + (lane >> 4) * 4;
#pragma unroll
        for (int r = 0; r < 4; ++r)
          ytile[(row0 + r) * 64 + col] = (f16)((acc[mi][ni][r] + bv) * SCALE);
      }
    }
    __syncthreads();
#pragma unroll
    for (int j = 0; j < 4; ++j) {
      int ci = tid * 4 + j;           // 0..1023 chunks of 8 f16
      int row = ci >> 3, off = (ci & 7) * 8;
      *(f16x8*)&qk16[(size_t)(bm + row) * 2048 + bn + off] =
          *(const f16x8*)&ytile[row * 64 + off];
    }
  } else {
    // v third: rows -> consecutive t, one f16x4 store (R20 path)
#pragma unroll
    for (int ni = 0; ni < 2; ++ni) {
      int col = bn + wc + ni * 16 + frow;
      float bv = bias[col];
#pragma unroll
      for (int mi = 0; mi < 4; ++mi) {
        int row0 = bm + wr + mi * 16 + (lane >> 4) * 4;
        int cc = col - 2048, hh = cc >> 6, d = cc & 63;
        int b = row0 >> 10, t0 = row0 & 1023;
        f16x4 o;
#pragma unroll
        for (int r = 0; r < 4; ++r) o[r] = (f16)(acc[mi][ni][r] + bv);
        *(f16x4*)&vT16[((size_t)(b * 16 + hh) * DEXT + d) * 1024 + t0] = o;
      }
    }
  }
}

// ---------- final proj GEMM (fp16 MFMA, 64x64 tile, BK=64, dbuf prefetch, XCD swizzle) --------
__global__ __launch_bounds__(256) void gemm_out_kernel(
    const f16* __restrict__ A, const f16* __restrict__ B,
    const float* __restrict__ bias, float* __restrict__ C) {
  __shared__ f16 As[2][64 * 64];
  __shared__ f16 Bs[2][64 * 64];
  const int tid = threadIdx.x;
  const int wid = tid >> 6, lane = tid & 63;
  // XCD-aware swizzle: 512 blocks, chunk 64 per XCD => 4 A row-panels resident per XCD L2
  const int bid = blockIdx.x;
  const int sbid = (bid & 7) * 64 + (bid >> 3);
  const int bm = (sbid >> 4) * 64, bn = (sbid & 15) * 64;
  const int wr = (wid >> 1) * 32, wc = (wid & 1) * 32;
  const int srow = lane >> 3, slot = lane & 7;
  const int frow = lane & 15, fkc = lane >> 4;
  f32x4 acc[2][2];
#pragma unroll
  for (int mi = 0; mi < 2; ++mi)
#pragma unroll
    for (int ni = 0; ni < 2; ++ni) acc[mi][ni] = f32x4{0.f, 0.f, 0.f, 0.f};

  auto STAGE = [&](int buf, int kt) {
#pragma unroll
    for (int i = 0; i < 2; ++i) {
      int row = i * 32 + wid * 8 + srow;
      gload16(&A[(size_t)(bm + row) * 1024 + kt + ((slot ^ (row & 7)) << 3)],
              (char*)As[buf] + i * 4096 + wid * 1024);
    }
#pragma unroll
    for (int i = 0; i < 2; ++i) {
      int row = i * 32 + wid * 8 + srow;
      gload16(&B[(size_t)(bn + row) * 1024 + kt + ((slot ^ (row & 7)) << 3)],
              (char*)Bs[buf] + i * 4096 + wid * 1024);
    }
  };
  STAGE(0, 0);
  for (int kt = 0; kt < 1024; kt += 64) {
    const int cur = (kt >> 6) & 1;
    if (kt + 64 < 1024) {
      STAGE(cur ^ 1, kt + 64);
      asm volatile("s_waitcnt vmcnt(4)" ::: "memory");
    } else {
      asm volatile("s_waitcnt vmcnt(0)" ::: "memory");
    }
    __builtin_amdgcn_s_barrier();
    asm volatile("" ::: "memory");
    f16x8 af[2][2], bf[2][2];
#pragma unroll
    for (int mi = 0; mi < 2; ++mi)
#pragma unroll
      for (int kk = 0; kk < 2; ++kk)
        af[mi][kk] = *(const f16x8*)&As[cur][sw8(wr + mi * 16 + frow, kk * 4 + fkc)];
#pragma unroll
    for (int ni = 0; ni < 2; ++ni)
#pragma unroll
      for (int kk = 0; kk < 2; ++kk)
        bf[ni][kk] = *(const f16x8*)&Bs[cur][sw8(wc + ni * 16 + frow, kk * 4 + fkc)];
#pragma unroll
    for (int kk = 0; kk < 2; ++kk)
#pragma unroll
      for (int mi = 0; mi < 2; ++mi)
#pragma unroll
        for (int ni = 0; ni < 2; ++ni)
          acc[mi][ni] = MFMA16(af[mi][kk], bf[ni][kk], acc[mi][ni], 0, 0, 0);
    asm volatile("" ::: "memory");
    __builtin_amdgcn_s_barrier();
  }
#pragma unroll
  for (int ni = 0; ni < 2; ++ni) {
    int col = bn + wc + ni * 16 + frow;
    float bv = bias[col];
#pragma unroll
    for (int mi = 0; mi < 2; ++mi) {
      int row0 = bm + wr + mi * 16 + (lane >> 4) * 4;
#pragma unroll
      for (int r = 0; r < 4; ++r)
        C[(size_t)(row0 + r) * 1024 + col] = acc[mi][ni][r] + bv;
    }
  }
}

// ---------- chunkS: recompute phi_k for chunk, then raw ST[d'][m] = vT_ext @ phi_k ------------
// XCD swizzle: 64 consecutive bc (4 full bh) per XCD -> vT/qk panels L2-resident
// ST rows 65..79 are provably unused downstream -> not stored (dead-traffic trim)
__global__ __launch_bounds__(256) void chunkS_kernel(const f16* __restrict__ qk16,
                                                     const f16* __restrict__ omT,
                                                     const f16* __restrict__ vT,
                                                     f16* __restrict__ ST) {
  __shared__ f16 om_s[8192];    // [128 m][64 d] sw8
  __shared__ f16 k_s[4096];     // [64 t][64 d] sw8
  __shared__ f16 pkT_s[8192];   // [128 m][64 t] sw8
  __shared__ f16 vt_s[5120];    // [80 d'][64 t] sw8
  __shared__ float nsq_s[64];
  const int tid = threadIdx.x;
  const int wid = tid >> 6, lane = tid & 63;
  const int bid = blockIdx.x;
  const int bc = (bid & 7) * 64 + (bid >> 3);
  const int bh = bc / NC, c = bc % NC;
  const int b = bh >> 4, h = bh & 15;
  const int tbase = c * LCH;
  const int frow = lane & 15, fkc = lane >> 4;
#pragma unroll
  for (int r = 0; r < 4; ++r) {
    int row = r * 32 + wid * 8 + (lane >> 3);
    gload16(omT + row * 64 + ((lane & 7) ^ (row & 7)) * 8,
            (char*)om_s + r * 4096 + wid * 1024);
  }
  {
    int rbase = b * 1024 + tbase, cbase = 1024 + h * 64;
#pragma unroll
    for (int r = 0; r < 2; ++r) {
      int row = r * 32 + wid * 8 + (lane >> 3);
      gload16(qk16 + (size_t)(rbase + row) * 2048 + cbase + ((lane & 7) ^ (row & 7)) * 8,
              (char*)k_s + r * 4096 + wid * 1024);
    }
  }
  for (int rr = wid; rr < 10; rr += 4) {
    int d = rr * 8 + (lane >> 3);
    gload16(vT + ((size_t)bh * DEXT + d) * 1024 + tbase + ((lane & 7) ^ (d & 7)) * 8,
            (char*)vt_s + rr * 1024);
  }
  __syncthreads();
  if (tid < 64) {
    float s = 0.f;
#pragma unroll
    for (int j = 0; j < 8; ++j) {
      f16x8 v = *(const f16x8*)&k_s[sw8(tid, j)];
#pragma unroll
      for (int e = 0; e < 8; ++e) { float f = (float)v[e]; s += f * f; }
    }
    nsq_s[tid] = s;
  }
  // phi_k: C[t][m] = k @ omT^T
  f32x4 acc2[8];
#pragma unroll
  for (int cm = 0; cm < 8; ++cm) acc2[cm] = f32x4{0.f, 0.f, 0.f, 0.f};
  {
    f16x8 af2[2], bf2;
#pragma unroll
    for (int kk = 0; kk < 2; ++kk)
      af2[kk] = *(const f16x8*)&k_s[sw8(wid * 16 + frow, kk * 4 + fkc)];
#pragma unroll
    for (int cm = 0; cm < 8; ++cm)
#pragma unroll
      for (int kk = 0; kk < 2; ++kk) {
        bf2 = *(const f16x8*)&om_s[sw8(cm * 16 + frow, kk * 4 + fkc)];
        acc2[cm] = MFMA16(af2[kk], bf2, acc2[cm], 0, 0, 0);
      }
  }
  __syncthreads();
  {
    int t0g = wid * 16 + (lane >> 4) * 4;
    int slot = t0g >> 3, sub = t0g & 4;
    float4 n4 = *(float4*)&nsq_s[t0g];
    float nn[4] = {-0.5f * n4.x, -0.5f * n4.y, -0.5f * n4.z, -0.5f * n4.w};
#pragma unroll
    for (int cm = 0; cm < 8; ++cm) {
      int m = cm * 16 + frow;
      f16x4 o;
#pragma unroll
      for (int r = 0; r < 4; ++r)
        o[r] = (f16)(__expf(acc2[cm][r] + nn[r]) * INV_SQRT_M);
      *(f16x4*)&pkT_s[m * 64 + ((slot ^ (m & 7)) << 3) + sub] = o;
    }
  }
  __syncthreads();
  // ST MFMA: acc[5][2] = vt_s (A rows d') x pkT_s (B rows m)
  f32x4 acc[5][2];
#pragma unroll
  for (int dt = 0; dt < 5; ++dt)
#pragma unroll
    for (int cj = 0; cj < 2; ++cj) acc[dt][cj] = f32x4{0.f, 0.f, 0.f, 0.f};
  f16x8 af, bf[2][2];
#pragma unroll
  for (int cj = 0; cj < 2; ++cj)
#pragma unroll
    for (int kk = 0; kk < 2; ++kk)
      bf[cj][kk] = *(const f16x8*)&pkT_s[sw8(wid * 32 + cj * 16 + frow, kk * 4 + fkc)];
#pragma unroll
  for (int dt = 0; dt < 5; ++dt)
#pragma unroll
    for (int kk = 0; kk < 2; ++kk) {
      af = *(const f16x8*)&vt_s[sw8(dt * 16 + frow, kk * 4 + fkc)];
#pragma unroll
      for (int cj = 0; cj < 2; ++cj)
        acc[dt][cj] = MFMA16(af, bf[cj][kk], acc[dt][cj], 0, 0, 0);
    }
  f16* dst = ST + (size_t)bc * (DEXT * 128);
#pragma unroll
  for (int dt = 0; dt < 5; ++dt)
#pragma unroll
    for (int cj = 0; cj < 2; ++cj) {
      int m = wid * 32 + cj * 16 + frow;
      int d0 = dt * 16 + (lane >> 4) * 4;
#pragma unroll
      for (int r = 0; r < 4; ++r)
        if (d0 + r <= 64)   // rows 65..79 are dead downstream
          dst[(size_t)(d0 + r) * 128 + m] = (f16)acc[dt][cj][r];
    }
}

// ---------- exclusive prefix over chunks: batched loads (1 round-trip), in-register scan ------
__global__ __launch_bounds__(256) void prefix_kernel(f16* __restrict__ ST) {
  int tid = threadIdx.x;
  int bh = blockIdx.x;
  int d = blockIdx.y * 16 + (tid >> 4), m0 = (tid & 15) * 8;
  if (d > 64) return;       // rows 65..79 unused downstream
  size_t base = (size_t)(bh * NC) * (DEXT * 128) + (size_t)d * 128 + m0;
  f16x8 v[NC];              // fully unrolled -> static indices -> registers (rule #20)
#pragma unroll
  for (int c = 0; c < NC; ++c)
    v[c] = *(const f16x8*)&ST[base + (size_t)c * (DEXT * 128)];
  float run[8] = {};
#pragma unroll
  for (int c = 0; c < NC; ++c) {
    f16x8 o;
#pragma unroll
    for (int j = 0; j < 8; ++j) {
      o[j] = (f16)run[j];
      run[j] += (float)v[c][j];
    }
    *(f16x8*)&ST[base + (size_t)c * (DEXT * 128)] = o;
  }
}

// ---------- intra: recompute phi_q/phi_k, QK^T -> causal A -> y; XCD swizzle ------------------
__global__ __launch_bounds__(256) void intra_kernel(const f16* __restrict__ qk16,
    const f16* __restrict__ omT, const f16* __restrict__ vT,
    const f16* __restrict__ ST, f16* __restrict__ y16) {
  __shared__ f16 pq_s[8192];    // [64 t][128 m] sw16
  __shared__ f16 pk_s[8192];    // [64 t][128 m] sw16
  __shared__ f16 vt_s[5120];    // [80 d'][64 t] sw8
  __shared__ f16 r2[16384];     // phase A: om(0..8191) q(8192..12287) k(12288..16383)
                                // phase B: st(0..10239) a(10240..14335)
  __shared__ float nsq_s[128];  // [0..63]=q, [64..127]=k
  __shared__ float den_s[64];
  f16* om_s = r2;
  f16* q_s  = r2 + 8192;
  f16* k_s  = r2 + 12288;
  f16* st_s = r2;
  f16* a_s  = r2 + 10240;
  const int tid = threadIdx.x;
  const int wid = tid >> 6, lane = tid & 63;
  const int bid = blockIdx.x;
  const int bc = (bid & 7) * 64 + (bid >> 3);
  const int bh = bc / NC, c = bc % NC;
  const int b = bh >> 4, h = bh & 15;
  const int tbase = c * LCH;
  const int frow = lane & 15, fkc = lane >> 4;
  // ---- stage om, q, k, vt ----
#pragma unroll
  for (int r = 0; r < 4; ++r) {
    int row = r * 32 + wid * 8 + (lane >> 3);
    gload16(omT + row * 64 + ((lane & 7) ^ (row & 7)) * 8,
            (char*)om_s + r * 4096 + wid * 1024);
  }
  {
    int rbase = b * 1024 + tbase;
#pragma unroll
    for (int r = 0; r < 2; ++r) {
      int row = r * 32 + wid * 8 + (lane >> 3);
      int csw = ((lane & 7) ^ (row & 7)) * 8;
      gload16(qk16 + (size_t)(rbase + row) * 2048 + h * 64 + csw,
              (char*)q_s + r * 4096 + wid * 1024);
      gload16(qk16 + (size_t)(rbase + row) * 2048 + 1024 + h * 64 + csw,
              (char*)k_s + r * 4096 + wid * 1024);
    }
  }
  for (int rr = wid; rr < 10; rr += 4) {
    int d = rr * 8 + (lane >> 3);
    gload16(vT + ((size_t)bh * DEXT + d) * 1024 + tbase + ((lane & 7) ^ (d & 7)) * 8,
            (char*)vt_s + rr * 1024);
  }
  __syncthreads();
  // ---- nsq for q and k rows ----
  if (tid < 128) {
    const f16* src = (tid < 64) ? q_s : k_s;
    int t = tid & 63;
    float s = 0.f;
#pragma unroll
    for (int j = 0; j < 8; ++j) {
      f16x8 v = *(const f16x8*)&src[sw8(t, j)];
#pragma unroll
      for (int e = 0; e < 8; ++e) { float f = (float)v[e]; s += f * f; }
    }
    nsq_s[tid] = s;
  }
  // ---- phi MFMAs: C[m][t] = omT @ {q,k}^T ----
  f32x4 acc1q[2][4], acc1k[2][4];
#pragma unroll
  for (int mi = 0; mi < 2; ++mi)
#pragma unroll
    for (int ct = 0; ct < 4; ++ct) {
      acc1q[mi][ct] = f32x4{0.f, 0.f, 0.f, 0.f};
      acc1k[mi][ct] = f32x4{0.f, 0.f, 0.f, 0.f};
    }
  {
    f16x8 af[2][2], bfq, bfk;
#pragma unroll
    for (int mi = 0; mi < 2; ++mi)
#pragma unroll
      for (int kk = 0; kk < 2; ++kk)
        af[mi][kk] = *(const f16x8*)&om_s[sw8(wid * 32 + mi * 16 + frow, kk * 4 + fkc)];
#pragma unroll
    for (int ct = 0; ct < 4; ++ct)
#pragma unroll
      for (int kk = 0; kk < 2; ++kk) {
        bfq = *(const f16x8*)&q_s[sw8(ct * 16 + frow, kk * 4 + fkc)];
        bfk = *(const f16x8*)&k_s[sw8(ct * 16 + frow, kk * 4 + fkc)];
#pragma unroll
        for (int mi = 0; mi < 2; ++mi) {
          acc1q[mi][ct] = MFMA16(af[mi][kk], bfq, acc1q[mi][ct], 0, 0, 0);
          acc1k[mi][ct] = MFMA16(af[mi][kk], bfk, acc1k[mi][ct], 0, 0, 0);
        }
      }
  }
  __syncthreads();
  // ---- exp + write pq_s, pk_s [t][128] sw16 (om/q/k now dead) ----
#pragma unroll
  for (int ct = 0; ct < 4; ++ct) {
    int t = ct * 16 + frow;
    float nq = -0.5f * nsq_s[t], nk = -0.5f * nsq_s[64 + t];
#pragma unroll
    for (int mi = 0; mi < 2; ++mi) {
      int m0 = wid * 32 + mi * 16 + (lane >> 4) * 4;
      int addr = t * 128 + (((m0 >> 3) ^ (t & 15)) << 3) + (m0 & 4);
      f16x4 oq, ok;
#pragma unroll
      for (int r = 0; r < 4; ++r) {
        oq[r] = (f16)(__expf(acc1q[mi][ct][r] + nq) * INV_SQRT_M);
        ok[r] = (f16)(__expf(acc1k[mi][ct][r] + nk) * INV_SQRT_M);
      }
      *(f16x4*)&pq_s[addr] = oq;
      *(f16x4*)&pk_s[addr] = ok;
    }
  }
  __syncthreads();
  // ---- issue ST gloads into r2[0..10240) (lands during QK^T); rows >64 skipped ----
#pragma unroll
  for (int r = 0; r < 5; ++r) {
    int row = r * 16 + wid * 4 + (lane >> 4);
    if (row <= 64) {     // rows 65..79 unused (stale finite LDS data lands in dead outputs)
      int col = ((lane & 15) ^ (row & 15)) * 8;
      gload16(ST + (size_t)bc * (DEXT * 128) + (size_t)row * 128 + col,
              (char*)st_s + r * 4096 + wid * 1024);
    }
  }
  // ---- QK^T swapped: A = pk rows tk, B = pq cols tq -> C'[tk][tq]; causal a_s[tq][tk] sw8 ----
  {
    f32x4 accq[4];
#pragma unroll
    for (int ct = 0; ct < 4; ++ct) accq[ct] = f32x4{0.f, 0.f, 0.f, 0.f};
    f16x8 af[4], bf;
#pragma unroll
    for (int kk = 0; kk < 4; ++kk)
      af[kk] = *(const f16x8*)&pk_s[sw16(wid * 16 + frow, kk * 4 + fkc)];
#pragma unroll
    for (int ct = 0; ct < 4; ++ct)
#pragma unroll
      for (int kk = 0; kk < 4; ++kk) {
        bf = *(const f16x8*)&pq_s[sw16(ct * 16 + frow, kk * 4 + fkc)];
        accq[ct] = MFMA16(af[kk], bf, accq[ct], 0, 0, 0);
      }
    int tkbase = wid * 16 + fkc * 4;
    int slot = tkbase >> 3, sub = tkbase & 4;
#pragma unroll
    for (int ct = 0; ct < 4; ++ct) {
      int tq = ct * 16 + frow;
      f16x4 av;
#pragma unroll
      for (int r = 0; r < 4; ++r)
        av[r] = (f16)((tkbase + r <= tq) ? accq[ct][r] : 0.f);
      *(f16x4*)&a_s[tq * 64 + ((slot ^ (tq & 7)) << 3) + sub] = av;
    }
  }
  asm volatile("s_waitcnt vmcnt(0)" ::: "memory");
  __syncthreads();
  // ---- phase 2: y_ext[ti][d'] = A @ vT_ext + phi_q @ ST_ext  (col 64 = den) ----
  f32x4 acc2[5];
#pragma unroll
  for (int ct = 0; ct < 5; ++ct) acc2[ct] = f32x4{0.f, 0.f, 0.f, 0.f};
  {
    f16x8 afA[2], afP[4], bfv;
#pragma unroll
    for (int kk = 0; kk < 2; ++kk)
      afA[kk] = *(const f16x8*)&a_s[sw8(wid * 16 + frow, kk * 4 + fkc)];
#pragma unroll
    for (int kk = 0; kk < 4; ++kk)
      afP[kk] = *(const f16x8*)&pq_s[sw16(wid * 16 + frow, kk * 4 + fkc)];
#pragma unroll
    for (int ct = 0; ct < 5; ++ct) {
#pragma unroll
      for (int kk = 0; kk < 2; ++kk) {
        bfv = *(const f16x8*)&vt_s[sw8(ct * 16 + frow, kk * 4 + fkc)];
        acc2[ct] = MFMA16(afA[kk], bfv, acc2[ct], 0, 0, 0);
      }
#pragma unroll
      for (int kk = 0; kk < 4; ++kk) {
        bfv = *(const f16x8*)&st_s[sw16(ct * 16 + frow, kk * 4 + fkc)];
        acc2[ct] = MFMA16(afP[kk], bfv, acc2[ct], 0, 0, 0);
      }
    }
  }
  if (frow == 0) {
    int t0g = wid * 16 + (lane >> 4) * 4;
#pragma unroll
    for (int r = 0; r < 4; ++r) den_s[t0g + r] = acc2[4][r];
  }
  __syncthreads();
  {
    int t0g = wid * 16 + (lane >> 4) * 4;
    float4 d4 = *(float4*)&den_s[t0g];
    float inv[4] = {1.f / (d4.x + EPSV), 1.f / (d4.y + EPSV),
                    1.f / (d4.z + EPSV), 1.f / (d4.w + EPSV)};
#pragma unroll
    for (int ct = 0; ct < 4; ++ct) {
      int d = ct * 16 + frow;
#pragma unroll
      for (int r = 0; r < 4; ++r) {
        int t = t0g + r;
        y16[(size_t)(b * 1024 + tbase + t) * 1024 + h * 64 + d] =
            (f16)(acc2[ct][r] * inv[r]);
      }
    }
  }
}

extern "C" void kernel_launch(void* const* d_in, const int* in_sizes, int n_in,
                              void* d_out, int out_size, void* d_ws, size_t ws_size,
                              hipStream_t stream) {
  const float* x      = (const float*)d_in[0];
  const float* W_attn = (const float*)d_in[1];
  const float* b_attn = (const float*)d_in[2];
  const float* W_proj = (const float*)d_in[3];
  const float* b_proj = (const float*)d_in[4];
  const float* omega  = (const float*)d_in[5];
  float* out = (float*)d_out;

  char* base = (char*)d_ws;
  f16* x16    = (f16*)(base);                     // 4,194,304 B
  f16* B16    = (f16*)(base + 4194304);           // 6,291,456 B (W_attn^T fp16)
  f16* qk16   = (f16*)(base + 10485760);          // 8,388,608 B (q,k pre-scaled)
  f16* vT16   = (f16*)(base + 18874368);          // 5,242,880 B (80 x 1024 per bh)
  f16* ST     = (f16*)(base + 24117248);          // 10,485,760 B (raw chunk sums, rows 0..64 live)
  f16* omT16  = (f16*)(base + 34603008);          // 16,384 B
  f16* B16p   = (f16*)(base + 34619392);          // 2,097,152 B (W_proj^T fp16)
  f16* y16    = (f16*)(base + 36716544);          // 4,194,304 B

  prep_kernel<<<6688, 256, 0, stream>>>(x, omega, W_attn, W_proj, x16, omT16, vT16, B16, B16p);
  gemm_qkv_kernel<<<768, 256, 0, stream>>>(x16, B16, b_attn, qk16, vT16);
  chunkS_kernel<<<512, 256, 0, stream>>>(qk16, omT16, vT16, ST);
  prefix_kernel<<<dim3(32, 5), 256, 0, stream>>>(ST);
  intra_kernel<<<512, 256, 0, stream>>>(qk16, omT16, vT16, ST, y16);
  gemm_out_kernel<<<512, 256, 0, stream>>>(y16, B16p, b_proj, out);
}

// Round 24
// 61.860 us; speedup vs baseline: 1.0255x; 1.0255x over previous
//
#include <hip/hip_runtime.h>
#include <math.h>

#define B_ 2
#define T_ 1024
#define C_ 1024
#define NH 16
#define DH 64
#define M_ 128
#define LCH 64
#define NC (T_/LCH)          // 16 chunks
#define DEXT 80              // 64 d + den-row(64) + pad to 5 tiles

constexpr float SCALE = 0.125f;              // 1/sqrt(64)
constexpr float EPSV = 1e-6f;
constexpr float INV_SQRT_M = 0.088388347648318447f;  // 1/sqrt(128)

typedef _Float16 f16;
typedef f16 f16x4 __attribute__((ext_vector_type(4)));
typedef f16 f16x8 __attribute__((ext_vector_type(8)));
typedef float f32x4 __attribute__((ext_vector_type(4)));

typedef const __attribute__((address_space(1))) void* as1_cvoid_p;
typedef __attribute__((address_space(3))) void* as3_void_p;

#define MFMA16 __builtin_amdgcn_mfma_f32_16x16x32_f16

__device__ __forceinline__ void gload16(const void* g, void* l) {
  __builtin_amdgcn_global_load_lds((as1_cvoid_p)g, (as3_void_p)l, 16, 0, 0);
}

// swizzled element index: row of (slots*8) f16, 16B-slot XOR'd by low row bits
__device__ __forceinline__ int sw8(int row, int slot)  { return row * 64  + ((slot ^ (row & 7))  << 3); }
__device__ __forceinline__ int sw16(int row, int slot) { return row * 128 + ((slot ^ (row & 15)) << 3); }

// ---------- prep: x->fp16, omega transpose, vT den-rows init, both weight transposes ----------
__global__ __launch_bounds__(256) void prep_kernel(const float* __restrict__ x,
                                                   const float* __restrict__ omega,
                                                   const float* __restrict__ Wa,
                                                   const float* __restrict__ Wp,
                                                   f16* __restrict__ x16,
                                                   f16* __restrict__ omT,
                                                   f16* __restrict__ vT,
                                                   f16* __restrict__ B16,
                                                   f16* __restrict__ B16p) {
  __shared__ float tile[32][33];
  int bid = blockIdx.x, tid = threadIdx.x;
  if (bid < 2048) {
    int i = (bid * 256 + tid) * 4;
    float4 v = *(const float4*)&x[i];
    f16x4 o = {(f16)v.x, (f16)v.y, (f16)v.z, (f16)v.w};
    *(f16x4*)&x16[i] = o;
  } else if (bid < 2080) {
    int e = (bid - 2048) * 256 + tid;
    int d = e >> 7, m = e & 127;
    omT[m * 64 + d] = (f16)omega[e];
  } else if (bid < 2592) {
    int idx = bid - 2080;             // 0..511
    int bh = idx >> 4, dr = idx & 15;
    f16 val = (dr == 0) ? (f16)1.0f : (f16)0.0f;
    f16x4 o = {val, val, val, val};
    *(f16x4*)&vT[((size_t)bh * DEXT + 64 + dr) * 1024 + tid * 4] = o;
  } else {
    int tb = bid - 2592;
    const float* in; f16* out; int N, n0, k0;
    if (tb < 3072) { in = Wa; out = B16;  N = 3072; n0 = (tb % 96) * 32; k0 = (tb / 96) * 32; }
    else { tb -= 3072; in = Wp; out = B16p; N = 1024; n0 = (tb & 31) * 32; k0 = (tb >> 5) * 32; }
    // vectorized transpose: 1 float4 load + 1 f16x4 store per thread (G13)
    {
      int row = tid >> 3, col4 = (tid & 7) * 4;       // tile row = k-rel, col = n-rel
      float4 v = *(const float4*)&in[(size_t)(k0 + row) * N + n0 + col4];
      tile[row][col4 + 0] = v.x; tile[row][col4 + 1] = v.y;
      tile[row][col4 + 2] = v.z; tile[row][col4 + 3] = v.w;
    }
    __syncthreads();
    {
      int n = tid >> 3, k4 = (tid & 7) * 4;
      f16x4 o = {(f16)tile[k4 + 0][n], (f16)tile[k4 + 1][n],
                 (f16)tile[k4 + 2][n], (f16)tile[k4 + 3][n]};
      *(f16x4*)&out[(size_t)(n0 + n) * 1024 + k0 + k4] = o;
    }
  }
}

// ---------- qkv GEMM (fp16 MFMA, 128x64 tile, BK=64, dbuf prefetch, XCD swizzle) --------------
__global__ __launch_bounds__(256) void gemm_qkv_kernel(
    const f16* __restrict__ A, const f16* __restrict__ B,
    const float* __restrict__ bias, f16* __restrict__ qk16, f16* __restrict__ vT16) {
  __shared__ f16 As[2][128 * 64];
  __shared__ f16 Bs[2][64 * 64];
  const int tid = threadIdx.x;
  const int wid = tid >> 6, lane = tid & 63;
  // XCD-aware swizzle: 768 blocks, chunk 96 per XCD => 2 A row-panels resident per XCD L2
  const int bid = blockIdx.x;
  const int sbid = (bid & 7) * 96 + (bid >> 3);
  const int bm = (sbid / 48) * 128, bn = (sbid % 48) * 64;
  const int wr = (wid >> 1) * 64, wc = (wid & 1) * 32;
  const int srow = lane >> 3, slot = lane & 7;
  const int frow = lane & 15, fkc = lane >> 4;
  f32x4 acc[4][2];
#pragma unroll
  for (int mi = 0; mi < 4; ++mi)
#pragma unroll
    for (int ni = 0; ni < 2; ++ni) acc[mi][ni] = f32x4{0.f, 0.f, 0.f, 0.f};

  auto STAGE = [&](int buf, int kt) {
#pragma unroll
    for (int i = 0; i < 4; ++i) {
      int row = i * 32 + wid * 8 + srow;
      gload16(&A[(size_t)(bm + row) * 1024 + kt + ((slot ^ (row & 7)) << 3)],
              (char*)As[buf] + i * 4096 + wid * 1024);
    }
#pragma unroll
    for (int i = 0; i < 2; ++i) {
      int row = i * 32 + wid * 8 + srow;
      gload16(&B[(size_t)(bn + row) * 1024 + kt + ((slot ^ (row & 7)) << 3)],
              (char*)Bs[buf] + i * 4096 + wid * 1024);
    }
  };
  STAGE(0, 0);
  for (int kt = 0; kt < 1024; kt += 64) {
    const int cur = (kt >> 6) & 1;
    if (kt + 64 < 1024) {
      STAGE(cur ^ 1, kt + 64);
      asm volatile("s_waitcnt vmcnt(6)" ::: "memory");
    } else {
      asm volatile("s_waitcnt vmcnt(0)" ::: "memory");
    }
    __builtin_amdgcn_s_barrier();
    asm volatile("" ::: "memory");
    f16x8 af[4][2], bf[2][2];
#pragma unroll
    for (int mi = 0; mi < 4; ++mi)
#pragma unroll
      for (int kk = 0; kk < 2; ++kk)
        af[mi][kk] = *(const f16x8*)&As[cur][sw8(wr + mi * 16 + frow, kk * 4 + fkc)];
#pragma unroll
    for (int ni = 0; ni < 2; ++ni)
#pragma unroll
      for (int kk = 0; kk < 2; ++kk)
        bf[ni][kk] = *(const f16x8*)&Bs[cur][sw8(wc + ni * 16 + frow, kk * 4 + fkc)];
#pragma unroll
    for (int kk = 0; kk < 2; ++kk)
#pragma unroll
      for (int mi = 0; mi < 4; ++mi)
#pragma unroll
        for (int ni = 0; ni < 2; ++ni)
          acc[mi][ni] = MFMA16(af[mi][kk], bf[ni][kk], acc[mi][ni], 0, 0, 0);
    asm volatile("" ::: "memory");
    __builtin_amdgcn_s_barrier();
  }
#pragma unroll
  for (int ni = 0; ni < 2; ++ni) {
    int col = bn + wc + ni * 16 + frow;
    float bv = bias[col];
#pragma unroll
    for (int mi = 0; mi < 4; ++mi) {
      int row0 = bm + wr + mi * 16 + (lane >> 4) * 4;
      if (col < 2048) {
#pragma unroll
        for (int r = 0; r < 4; ++r)
          qk16[(size_t)(row0 + r) * 2048 + col] = (f16)((acc[mi][ni][r] + bv) * SCALE);
      } else {
        // v-third: rows row0..row0+3 -> consecutive t, same (b,hh,d) -> one f16x4 store
        int cc = col - 2048, hh = cc >> 6, d = cc & 63;
        int b = row0 >> 10, t0 = row0 & 1023;
        f16x4 o;
#pragma unroll
        for (int r = 0; r < 4; ++r) o[r] = (f16)(acc[mi][ni][r] + bv);
        *(f16x4*)&vT16[((size_t)(b * 16 + hh) * DEXT + d) * 1024 + t0] = o;
      }
    }
  }
}

// ---------- final proj GEMM (fp16 MFMA, 64x64 tile, BK=64, dbuf prefetch, XCD swizzle) --------
__global__ __launch_bounds__(256) void gemm_out_kernel(
    const f16* __restrict__ A, const f16* __restrict__ B,
    const float* __restrict__ bias, float* __restrict__ C) {
  __shared__ f16 As[2][64 * 64];
  __shared__ f16 Bs[2][64 * 64];
  const int tid = threadIdx.x;
  const int wid = tid >> 6, lane = tid & 63;
  // XCD-aware swizzle: 512 blocks, chunk 64 per XCD => 4 A row-panels resident per XCD L2
  const int bid = blockIdx.x;
  const int sbid = (bid & 7) * 64 + (bid >> 3);
  const int bm = (sbid >> 4) * 64, bn = (sbid & 15) * 64;
  const int wr = (wid >> 1) * 32, wc = (wid & 1) * 32;
  const int srow = lane >> 3, slot = lane & 7;
  const int frow = lane & 15, fkc = lane >> 4;
  f32x4 acc[2][2];
#pragma unroll
  for (int mi = 0; mi < 2; ++mi)
#pragma unroll
    for (int ni = 0; ni < 2; ++ni) acc[mi][ni] = f32x4{0.f, 0.f, 0.f, 0.f};

  auto STAGE = [&](int buf, int kt) {
#pragma unroll
    for (int i = 0; i < 2; ++i) {
      int row = i * 32 + wid * 8 + srow;
      gload16(&A[(size_t)(bm + row) * 1024 + kt + ((slot ^ (row & 7)) << 3)],
              (char*)As[buf] + i * 4096 + wid * 1024);
    }
#pragma unroll
    for (int i = 0; i < 2; ++i) {
      int row = i * 32 + wid * 8 + srow;
      gload16(&B[(size_t)(bn + row) * 1024 + kt + ((slot ^ (row & 7)) << 3)],
              (char*)Bs[buf] + i * 4096 + wid * 1024);
    }
  };
  STAGE(0, 0);
  for (int kt = 0; kt < 1024; kt += 64) {
    const int cur = (kt >> 6) & 1;
    if (kt + 64 < 1024) {
      STAGE(cur ^ 1, kt + 64);
      asm volatile("s_waitcnt vmcnt(4)" ::: "memory");
    } else {
      asm volatile("s_waitcnt vmcnt(0)" ::: "memory");
    }
    __builtin_amdgcn_s_barrier();
    asm volatile("" ::: "memory");
    f16x8 af[2][2], bf[2][2];
#pragma unroll
    for (int mi = 0; mi < 2; ++mi)
#pragma unroll
      for (int kk = 0; kk < 2; ++kk)
        af[mi][kk] = *(const f16x8*)&As[cur][sw8(wr + mi * 16 + frow, kk * 4 + fkc)];
#pragma unroll
    for (int ni = 0; ni < 2; ++ni)
#pragma unroll
      for (int kk = 0; kk < 2; ++kk)
        bf[ni][kk] = *(const f16x8*)&Bs[cur][sw8(wc + ni * 16 + frow, kk * 4 + fkc)];
#pragma unroll
    for (int kk = 0; kk < 2; ++kk)
#pragma unroll
      for (int mi = 0; mi < 2; ++mi)
#pragma unroll
        for (int ni = 0; ni < 2; ++ni)
          acc[mi][ni] = MFMA16(af[mi][kk], bf[ni][kk], acc[mi][ni], 0, 0, 0);
    asm volatile("" ::: "memory");
    __builtin_amdgcn_s_barrier();
  }
#pragma unroll
  for (int ni = 0; ni < 2; ++ni) {
    int col = bn + wc + ni * 16 + frow;
    float bv = bias[col];
#pragma unroll
    for (int mi = 0; mi < 2; ++mi) {
      int row0 = bm + wr + mi * 16 + (lane >> 4) * 4;
#pragma unroll
      for (int r = 0; r < 4; ++r)
        C[(size_t)(row0 + r) * 1024 + col] = acc[mi][ni][r] + bv;
    }
  }
}

// ---------- chunkS: recompute phi_k for chunk, then raw ST[d'][m] = vT_ext @ phi_k ------------
// XCD swizzle: 64 consecutive bc (4 full bh) per XCD -> vT/qk panels L2-resident
// ST rows 65..79 are provably unused downstream -> not stored (dead-traffic trim)
__global__ __launch_bounds__(256) void chunkS_kernel(const f16* __restrict__ qk16,
                                                     const f16* __restrict__ omT,
                                                     const f16* __restrict__ vT,
                                                     f16* __restrict__ ST) {
  __shared__ f16 om_s[8192];    // [128 m][64 d] sw8
  __shared__ f16 k_s[4096];     // [64 t][64 d] sw8
  __shared__ f16 pkT_s[8192];   // [128 m][64 t] sw8
  __shared__ f16 vt_s[5120];    // [80 d'][64 t] sw8
  __shared__ float nsq_s[64];
  const int tid = threadIdx.x;
  const int wid = tid >> 6, lane = tid & 63;
  const int bid = blockIdx.x;
  const int bc = (bid & 7) * 64 + (bid >> 3);
  const int bh = bc / NC, c = bc % NC;
  const int b = bh >> 4, h = bh & 15;
  const int tbase = c * LCH;
  const int frow = lane & 15, fkc = lane >> 4;
#pragma unroll
  for (int r = 0; r < 4; ++r) {
    int row = r * 32 + wid * 8 + (lane >> 3);
    gload16(omT + row * 64 + ((lane & 7) ^ (row & 7)) * 8,
            (char*)om_s + r * 4096 + wid * 1024);
  }
  {
    int rbase = b * 1024 + tbase, cbase = 1024 + h * 64;
#pragma unroll
    for (int r = 0; r < 2; ++r) {
      int row = r * 32 + wid * 8 + (lane >> 3);
      gload16(qk16 + (size_t)(rbase + row) * 2048 + cbase + ((lane & 7) ^ (row & 7)) * 8,
              (char*)k_s + r * 4096 + wid * 1024);
    }
  }
  for (int rr = wid; rr < 10; rr += 4) {
    int d = rr * 8 + (lane >> 3);
    gload16(vT + ((size_t)bh * DEXT + d) * 1024 + tbase + ((lane & 7) ^ (d & 7)) * 8,
            (char*)vt_s + rr * 1024);
  }
  __syncthreads();
  if (tid < 64) {
    float s = 0.f;
#pragma unroll
    for (int j = 0; j < 8; ++j) {
      f16x8 v = *(const f16x8*)&k_s[sw8(tid, j)];
#pragma unroll
      for (int e = 0; e < 8; ++e) { float f = (float)v[e]; s += f * f; }
    }
    nsq_s[tid] = s;
  }
  // phi_k: C[t][m] = k @ omT^T
  f32x4 acc2[8];
#pragma unroll
  for (int cm = 0; cm < 8; ++cm) acc2[cm] = f32x4{0.f, 0.f, 0.f, 0.f};
  {
    f16x8 af2[2], bf2;
#pragma unroll
    for (int kk = 0; kk < 2; ++kk)
      af2[kk] = *(const f16x8*)&k_s[sw8(wid * 16 + frow, kk * 4 + fkc)];
#pragma unroll
    for (int cm = 0; cm < 8; ++cm)
#pragma unroll
      for (int kk = 0; kk < 2; ++kk) {
        bf2 = *(const f16x8*)&om_s[sw8(cm * 16 + frow, kk * 4 + fkc)];
        acc2[cm] = MFMA16(af2[kk], bf2, acc2[cm], 0, 0, 0);
      }
  }
  __syncthreads();
  {
    int t0g = wid * 16 + (lane >> 4) * 4;
    int slot = t0g >> 3, sub = t0g & 4;
    float4 n4 = *(float4*)&nsq_s[t0g];
    float nn[4] = {-0.5f * n4.x, -0.5f * n4.y, -0.5f * n4.z, -0.5f * n4.w};
#pragma unroll
    for (int cm = 0; cm < 8; ++cm) {
      int m = cm * 16 + frow;
      f16x4 o;
#pragma unroll
      for (int r = 0; r < 4; ++r)
        o[r] = (f16)(__expf(acc2[cm][r] + nn[r]) * INV_SQRT_M);
      *(f16x4*)&pkT_s[m * 64 + ((slot ^ (m & 7)) << 3) + sub] = o;
    }
  }
  __syncthreads();
  // ST MFMA: acc[5][2] = vt_s (A rows d') x pkT_s (B rows m)
  f32x4 acc[5][2];
#pragma unroll
  for (int dt = 0; dt < 5; ++dt)
#pragma unroll
    for (int cj = 0; cj < 2; ++cj) acc[dt][cj] = f32x4{0.f, 0.f, 0.f, 0.f};
  f16x8 af, bf[2][2];
#pragma unroll
  for (int cj = 0; cj < 2; ++cj)
#pragma unroll
    for (int kk = 0; kk < 2; ++kk)
      bf[cj][kk] = *(const f16x8*)&pkT_s[sw8(wid * 32 + cj * 16 + frow, kk * 4 + fkc)];
#pragma unroll
  for (int dt = 0; dt < 5; ++dt)
#pragma unroll
    for (int kk = 0; kk < 2; ++kk) {
      af = *(const f16x8*)&vt_s[sw8(dt * 16 + frow, kk * 4 + fkc)];
#pragma unroll
      for (int cj = 0; cj < 2; ++cj)
        acc[dt][cj] = MFMA16(af, bf[cj][kk], acc[dt][cj], 0, 0, 0);
    }
  f16* dst = ST + (size_t)bc * (DEXT * 128);
#pragma unroll
  for (int dt = 0; dt < 5; ++dt)
#pragma unroll
    for (int cj = 0; cj < 2; ++cj) {
      int m = wid * 32 + cj * 16 + frow;
      int d0 = dt * 16 + (lane >> 4) * 4;
#pragma unroll
      for (int r = 0; r < 4; ++r)
        if (d0 + r <= 64)   // rows 65..79 are dead downstream
          dst[(size_t)(d0 + r) * 128 + m] = (f16)acc[dt][cj][r];
    }
}

// ---------- exclusive prefix over chunks: batched loads (1 round-trip), in-register scan ------
__global__ __launch_bounds__(256) void prefix_kernel(f16* __restrict__ ST) {
  int tid = threadIdx.x;
  int bh = blockIdx.x;
  int d = blockIdx.y * 16 + (tid >> 4), m0 = (tid & 15) * 8;
  if (d > 64) return;       // rows 65..79 unused downstream
  size_t base = (size_t)(bh * NC) * (DEXT * 128) + (size_t)d * 128 + m0;
  f16x8 v[NC];              // fully unrolled -> static indices -> registers (rule #20)
#pragma unroll
  for (int c = 0; c < NC; ++c)
    v[c] = *(const f16x8*)&ST[base + (size_t)c * (DEXT * 128)];
  float run[8] = {};
#pragma unroll
  for (int c = 0; c < NC; ++c) {
    f16x8 o;
#pragma unroll
    for (int j = 0; j < 8; ++j) {
      o[j] = (f16)run[j];
      run[j] += (float)v[c][j];
    }
    *(f16x8*)&ST[base + (size_t)c * (DEXT * 128)] = o;
  }
}

// ---------- intra: recompute phi_q/phi_k, QK^T -> causal A -> y; XCD swizzle ------------------
__global__ __launch_bounds__(256) void intra_kernel(const f16* __restrict__ qk16,
    const f16* __restrict__ omT, const f16* __restrict__ vT,
    const f16* __restrict__ ST, f16* __restrict__ y16) {
  __shared__ f16 pq_s[8192];    // [64 t][128 m] sw16
  __shared__ f16 pk_s[8192];    // [64 t][128 m] sw16
  __shared__ f16 vt_s[5120];    // [80 d'][64 t] sw8
  __shared__ f16 r2[16384];     // phase A: om(0..8191) q(8192..12287) k(12288..16383)
                                // phase B: st(0..10239) a(10240..14335)
  __shared__ float nsq_s[128];  // [0..63]=q, [64..127]=k
  __shared__ float den_s[64];
  f16* om_s = r2;
  f16* q_s  = r2 + 8192;
  f16* k_s  = r2 + 12288;
  f16* st_s = r2;
  f16* a_s  = r2 + 10240;
  const int tid = threadIdx.x;
  const int wid = tid >> 6, lane = tid & 63;
  const int bid = blockIdx.x;
  const int bc = (bid & 7) * 64 + (bid >> 3);
  const int bh = bc / NC, c = bc % NC;
  const int b = bh >> 4, h = bh & 15;
  const int tbase = c * LCH;
  const int frow = lane & 15, fkc = lane >> 4;
  // ---- stage om, q, k, vt ----
#pragma unroll
  for (int r = 0; r < 4; ++r) {
    int row = r * 32 + wid * 8 + (lane >> 3);
    gload16(omT + row * 64 + ((lane & 7) ^ (row & 7)) * 8,
            (char*)om_s + r * 4096 + wid * 1024);
  }
  {
    int rbase = b * 1024 + tbase;
#pragma unroll
    for (int r = 0; r < 2; ++r) {
      int row = r * 32 + wid * 8 + (lane >> 3);
      int csw = ((lane & 7) ^ (row & 7)) * 8;
      gload16(qk16 + (size_t)(rbase + row) * 2048 + h * 64 + csw,
              (char*)q_s + r * 4096 + wid * 1024);
      gload16(qk16 + (size_t)(rbase + row) * 2048 + 1024 + h * 64 + csw,
              (char*)k_s + r * 4096 + wid * 1024);
    }
  }
  for (int rr = wid; rr < 10; rr += 4) {
    int d = rr * 8 + (lane >> 3);
    gload16(vT + ((size_t)bh * DEXT + d) * 1024 + tbase + ((lane & 7) ^ (d & 7)) * 8,
            (char*)vt_s + rr * 1024);
  }
  __syncthreads();
  // ---- nsq for q and k rows ----
  if (tid < 128) {
    const f16* src = (tid < 64) ? q_s : k_s;
    int t = tid & 63;
    float s = 0.f;
#pragma unroll
    for (int j = 0; j < 8; ++j) {
      f16x8 v = *(const f16x8*)&src[sw8(t, j)];
#pragma unroll
      for (int e = 0; e < 8; ++e) { float f = (float)v[e]; s += f * f; }
    }
    nsq_s[tid] = s;
  }
  // ---- phi MFMAs: C[m][t] = omT @ {q,k}^T ----
  f32x4 acc1q[2][4], acc1k[2][4];
#pragma unroll
  for (int mi = 0; mi < 2; ++mi)
#pragma unroll
    for (int ct = 0; ct < 4; ++ct) {
      acc1q[mi][ct] = f32x4{0.f, 0.f, 0.f, 0.f};
      acc1k[mi][ct] = f32x4{0.f, 0.f, 0.f, 0.f};
    }
  {
    f16x8 af[2][2], bfq, bfk;
#pragma unroll
    for (int mi = 0; mi < 2; ++mi)
#pragma unroll
      for (int kk = 0; kk < 2; ++kk)
        af[mi][kk] = *(const f16x8*)&om_s[sw8(wid * 32 + mi * 16 + frow, kk * 4 + fkc)];
#pragma unroll
    for (int ct = 0; ct < 4; ++ct)
#pragma unroll
      for (int kk = 0; kk < 2; ++kk) {
        bfq = *(const f16x8*)&q_s[sw8(ct * 16 + frow, kk * 4 + fkc)];
        bfk = *(const f16x8*)&k_s[sw8(ct * 16 + frow, kk * 4 + fkc)];
#pragma unroll
        for (int mi = 0; mi < 2; ++mi) {
          acc1q[mi][ct] = MFMA16(af[mi][kk], bfq, acc1q[mi][ct], 0, 0, 0);
          acc1k[mi][ct] = MFMA16(af[mi][kk], bfk, acc1k[mi][ct], 0, 0, 0);
        }
      }
  }
  __syncthreads();
  // ---- exp + write pq_s, pk_s [t][128] sw16 (om/q/k now dead) ----
#pragma unroll
  for (int ct = 0; ct < 4; ++ct) {
    int t = ct * 16 + frow;
    float nq = -0.5f * nsq_s[t], nk = -0.5f * nsq_s[64 + t];
#pragma unroll
    for (int mi = 0; mi < 2; ++mi) {
      int m0 = wid * 32 + mi * 16 + (lane >> 4) * 4;
      int addr = t * 128 + (((m0 >> 3) ^ (t & 15)) << 3) + (m0 & 4);
      f16x4 oq, ok;
#pragma unroll
      for (int r = 0; r < 4; ++r) {
        oq[r] = (f16)(__expf(acc1q[mi][ct][r] + nq) * INV_SQRT_M);
        ok[r] = (f16)(__expf(acc1k[mi][ct][r] + nk) * INV_SQRT_M);
      }
      *(f16x4*)&pq_s[addr] = oq;
      *(f16x4*)&pk_s[addr] = ok;
    }
  }
  __syncthreads();
  // ---- issue ST gloads into r2[0..10240) (lands during QK^T); rows >64 skipped ----
#pragma unroll
  for (int r = 0; r < 5; ++r) {
    int row = r * 16 + wid * 4 + (lane >> 4);
    if (row <= 64) {     // rows 65..79 unused (stale finite LDS data lands in dead outputs)
      int col = ((lane & 15) ^ (row & 15)) * 8;
      gload16(ST + (size_t)bc * (DEXT * 128) + (size_t)row * 128 + col,
              (char*)st_s + r * 4096 + wid * 1024);
    }
  }
  // ---- QK^T swapped: A = pk rows tk, B = pq cols tq -> C'[tk][tq]; causal a_s[tq][tk] sw8 ----
  {
    f32x4 accq[4];
#pragma unroll
    for (int ct = 0; ct < 4; ++ct) accq[ct] = f32x4{0.f, 0.f, 0.f, 0.f};
    f16x8 af[4], bf;
#pragma unroll
    for (int kk = 0; kk < 4; ++kk)
      af[kk] = *(const f16x8*)&pk_s[sw16(wid * 16 + frow, kk * 4 + fkc)];
#pragma unroll
    for (int ct = 0; ct < 4; ++ct)
#pragma unroll
      for (int kk = 0; kk < 4; ++kk) {
        bf = *(const f16x8*)&pq_s[sw16(ct * 16 + frow, kk * 4 + fkc)];
        accq[ct] = MFMA16(af[kk], bf, accq[ct], 0, 0, 0);
      }
    int tkbase = wid * 16 + fkc * 4;
    int slot = tkbase >> 3, sub = tkbase & 4;
#pragma unroll
    for (int ct = 0; ct < 4; ++ct) {
      int tq = ct * 16 + frow;
      f16x4 av;
#pragma unroll
      for (int r = 0; r < 4; ++r)
        av[r] = (f16)((tkbase + r <= tq) ? accq[ct][r] : 0.f);
      *(f16x4*)&a_s[tq * 64 + ((slot ^ (tq & 7)) << 3) + sub] = av;
    }
  }
  asm volatile("s_waitcnt vmcnt(0)" ::: "memory");
  __syncthreads();
  // ---- phase 2: y_ext[ti][d'] = A @ vT_ext + phi_q @ ST_ext  (col 64 = den) ----
  f32x4 acc2[5];
#pragma unroll
  for (int ct = 0; ct < 5; ++ct) acc2[ct] = f32x4{0.f, 0.f, 0.f, 0.f};
  {
    f16x8 afA[2], afP[4], bfv;
#pragma unroll
    for (int kk = 0; kk < 2; ++kk)
      afA[kk] = *(const f16x8*)&a_s[sw8(wid * 16 + frow, kk * 4 + fkc)];
#pragma unroll
    for (int kk = 0; kk < 4; ++kk)
      afP[kk] = *(const f16x8*)&pq_s[sw16(wid * 16 + frow, kk * 4 + fkc)];
#pragma unroll
    for (int ct = 0; ct < 5; ++ct) {
#pragma unroll
      for (int kk = 0; kk < 2; ++kk) {
        bfv = *(const f16x8*)&vt_s[sw8(ct * 16 + frow, kk * 4 + fkc)];
        acc2[ct] = MFMA16(afA[kk], bfv, acc2[ct], 0, 0, 0);
      }
#pragma unroll
      for (int kk = 0; kk < 4; ++kk) {
        bfv = *(const f16x8*)&st_s[sw16(ct * 16 + frow, kk * 4 + fkc)];
        acc2[ct] = MFMA16(afP[kk], bfv, acc2[ct], 0, 0, 0);
      }
    }
  }
  if (frow == 0) {
    int t0g = wid * 16 + (lane >> 4) * 4;
#pragma unroll
    for (int r = 0; r < 4; ++r) den_s[t0g + r] = acc2[4][r];
  }
  __syncthreads();
  {
    int t0g = wid * 16 + (lane >> 4) * 4;
    float4 d4 = *(float4*)&den_s[t0g];
    float inv[4] = {1.f / (d4.x + EPSV), 1.f / (d4.y + EPSV),
                    1.f / (d4.z + EPSV), 1.f / (d4.w + EPSV)};
#pragma unroll
    for (int ct = 0; ct < 4; ++ct) {
      int d = ct * 16 + frow;
#pragma unroll
      for (int r = 0; r < 4; ++r) {
        int t = t0g + r;
        y16[(size_t)(b * 1024 + tbase + t) * 1024 + h * 64 + d] =
            (f16)(acc2[ct][r] * inv[r]);
      }
    }
  }
}

extern "C" void kernel_launch(void* const* d_in, const int* in_sizes, int n_in,
                              void* d_out, int out_size, void* d_ws, size_t ws_size,
                              hipStream_t stream) {
  const float* x      = (const float*)d_in[0];
  const float* W_attn = (const float*)d_in[1];
  const float* b_attn = (const float*)d_in[2];
  const float* W_proj = (const float*)d_in[3];
  const float* b_proj = (const float*)d_in[4];
  const float* omega  = (const float*)d_in[5];
  float* out = (float*)d_out;

  char* base = (char*)d_ws;
  f16* x16    = (f16*)(base);                     // 4,194,304 B
  f16* B16    = (f16*)(base + 4194304);           // 6,291,456 B (W_attn^T fp16)
  f16* qk16   = (f16*)(base + 10485760);          // 8,388,608 B (q,k pre-scaled)
  f16* vT16   = (f16*)(base + 18874368);          // 5,242,880 B (80 x 1024 per bh)
  f16* ST     = (f16*)(base + 24117248);          // 10,485,760 B (raw chunk sums, rows 0..64 live)
  f16* omT16  = (f16*)(base + 34603008);          // 16,384 B
  f16* B16p   = (f16*)(base + 34619392);          // 2,097,152 B (W_proj^T fp16)
  f16* y16    = (f16*)(base + 36716544);          // 4,194,304 B

  prep_kernel<<<6688, 256, 0, stream>>>(x, omega, W_attn, W_proj, x16, omT16, vT16, B16, B16p);
  gemm_qkv_kernel<<<768, 256, 0, stream>>>(x16, B16, b_attn, qk16, vT16);
  chunkS_kernel<<<512, 256, 0, stream>>>(qk16, omT16, vT16, ST);
  prefix_kernel<<<dim3(32, 5), 256, 0, stream>>>(ST);
  intra_kernel<<<512, 256, 0, stream>>>(qk16, omT16, vT16, ST, y16);
  gemm_out_kernel<<<512, 256, 0, stream>>>(y16, B16p, b_proj, out);
}